// Round 4
// baseline (354.328 us; speedup 1.0000x reference)
//
#include <hip/hip_runtime.h>

// ---------- types / helpers ----------
typedef __attribute__((ext_vector_type(4))) float f32x4;
typedef __attribute__((ext_vector_type(8))) __bf16 bf16x8;

__device__ __forceinline__ unsigned short f2b(float f) {
  unsigned int u = __builtin_bit_cast(unsigned int, f);
  u = (u + 0x7fffu + ((u >> 16) & 1u)) >> 16;
  return (unsigned short)u;
}
__device__ __forceinline__ float b2f(unsigned short h) {
  unsigned int u = ((unsigned int)h) << 16;
  return __builtin_bit_cast(float, u);
}
__device__ __forceinline__ void gl_lds16(const void* g, void* l) {
  __builtin_amdgcn_global_load_lds(
      (const __attribute__((address_space(1))) void*)g,
      (__attribute__((address_space(3))) void*)l, 16, 0, 0);
}

// ---------- fp32 -> bf16 cast ----------
__global__ void cast_kernel(const float* __restrict__ src,
                            unsigned short* __restrict__ dst, int n4) {
  int i = blockIdx.x * blockDim.x + threadIdx.x;
  if (i >= n4) return;
  float4 v = ((const float4*)src)[i];
  ushort4 o;
  o.x = f2b(v.x); o.y = f2b(v.y); o.z = f2b(v.z); o.w = f2b(v.w);
  ((ushort4*)dst)[i] = o;
}

__global__ void cast4_kernel(const float* __restrict__ s0, const float* __restrict__ s1,
                             const float* __restrict__ s2, const float* __restrict__ s3,
                             unsigned short* __restrict__ d0, unsigned short* __restrict__ d1,
                             unsigned short* __restrict__ d2, unsigned short* __restrict__ d3,
                             int n4) {
  int i = blockIdx.x * blockDim.x + threadIdx.x;
  if (i >= n4) return;
  const float* src = blockIdx.y == 0 ? s0 : blockIdx.y == 1 ? s1 : blockIdx.y == 2 ? s2 : s3;
  unsigned short* dst = blockIdx.y == 0 ? d0 : blockIdx.y == 1 ? d1 : blockIdx.y == 2 ? d2 : d3;
  float4 v = ((const float4*)src)[i];
  ushort4 o;
  o.x = f2b(v.x); o.y = f2b(v.y); o.z = f2b(v.z); o.w = f2b(v.w);
  ((ushort4*)dst)[i] = o;
}

// ---------- RoPE cos/sin table ----------
__global__ void rope_table_kernel(float2* __restrict__ tab) {
  int idx = blockIdx.x * blockDim.x + threadIdx.x;
  int l = idx >> 6, i = idx & 63;
  float freq = powf(10000.0f, -(float)(2 * i) / 128.0f);
  float th = (float)l * freq;
  tab[idx] = make_float2(cosf(th), sinf(th));
}

// ---------- RoPE apply; q additionally pre-scaled by 1/sqrt(Dh)*log2(e) ----------
__global__ void rope_apply_kernel(unsigned short* __restrict__ qb,
                                  unsigned short* __restrict__ kb,
                                  unsigned short* __restrict__ vb,
                                  float* __restrict__ kout,
                                  float* __restrict__ vout,
                                  const float2* __restrict__ tab) {
  const float QS = 0.12751743f;  // (1/sqrt(128)) * log2(e)
  int z = blockIdx.y;
  int p = blockIdx.x * blockDim.x + threadIdx.x;
  int i = p & 63;
  int t = p >> 6;
  int h = t & 15; t >>= 4;
  int l = t & 2047;
  int b = t >> 11;
  int base = ((b * 2048 + l) * 2048) + h * 128 + 2 * i;
  int obase = ((b * 16 + h) * 2048 + l) * 128 + 2 * i;
  if (z == 2) {
    vout[obase] = b2f(vb[base]);
    vout[obase + 1] = b2f(vb[base + 1]);
  } else {
    unsigned short* buf = z ? kb : qb;
    float x1 = b2f(buf[base]), x2 = b2f(buf[base + 1]);
    float2 cs = tab[l * 64 + i];
    float r1 = x1 * cs.x - x2 * cs.y;
    float r2 = x1 * cs.y + x2 * cs.x;
    if (z == 1) {
      buf[base] = f2b(r1);
      buf[base + 1] = f2b(r2);
      kout[obase] = r1; kout[obase + 1] = r2;
    } else {
      buf[base] = f2b(r1 * QS);
      buf[base + 1] = f2b(r2 * QS);
    }
  }
}

// ---------- tiled transpose: vb (B,L,D) head-slice -> vt (B,H,Dh,L) ----------
__global__ __launch_bounds__(256) void transpose_v_kernel(const unsigned short* __restrict__ vb,
                                                          unsigned short* __restrict__ vt) {
  __shared__ unsigned short t[32][33];
  int bz = blockIdx.z;
  int b = bz >> 4, h = bz & 15;
  int l0 = blockIdx.x * 32, d0 = blockIdx.y * 32;
  const unsigned short* src = vb + (size_t)b * 2048 * 2048 + h * 128;
  unsigned short* dst = vt + (size_t)bz * 128 * 2048;
  int tx = threadIdx.x & 31, ty = threadIdx.x >> 5;
#pragma unroll
  for (int i = 0; i < 4; ++i)
    t[ty + 8 * i][tx] = src[(size_t)(l0 + ty + 8 * i) * 2048 + d0 + tx];
  __syncthreads();
#pragma unroll
  for (int i = 0; i < 4; ++i)
    dst[(size_t)(d0 + ty + 8 * i) * 2048 + l0 + tx] = t[tx][ty + 8 * i];
}

// ---------- GEMM v2: BM=128 x BN=256 x BK=64, 8 waves (2Mx4N), swizzled LDS, ----------
// ---------- 1 barrier / K-tile, issue-early staging, setprio, XCD swizzle    ----------
// C = A[4096xK] * W[NxK]^T ; output cols grouped into 2048-wide matrices (QKV fusion).
template <int NBN, int OUT_F32>
__global__ __launch_bounds__(512, 2) void gemm2(const unsigned short* __restrict__ A,
                                                const unsigned short* __restrict__ W,
                                                void* __restrict__ C) {
  __shared__ unsigned short As[2][128 * 64];  // 32 KB
  __shared__ unsigned short Bs[2][256 * 64];  // 64 KB
  const int K = 2048, NT = 32;
  int tid = threadIdx.x, lane = tid & 63, w = tid >> 6;
  int wr = w >> 2, wc = w & 3;
  int ln = lane & 15, kg = lane >> 4;

  // XCD-aware bijective swizzle (gridDim.x divisible by 8)
  int cpx = gridDim.x >> 3;
  int swz = (blockIdx.x & 7) * cpx + (blockIdx.x >> 3);
  int bm = swz / NBN, bn = swz % NBN;
  int m0 = bm * 128, n0 = bn * 256;

  // staging geometry: thread covers row trow of each 64-row chunk, slot pre-swizzled
  int trow = tid >> 3;
  int sg = ((tid & 7) ^ (trow & 7)) * 8;
  const unsigned short* pA0 = A + (size_t)(m0 + trow) * K + sg;
  const unsigned short* pA1 = pA0 + (size_t)64 * K;
  const unsigned short* pB0 = W + (size_t)(n0 + trow) * K + sg;
  const unsigned short* pB1 = pB0 + (size_t)64 * K;
  const unsigned short* pB2 = pB0 + (size_t)128 * K;
  const unsigned short* pB3 = pB0 + (size_t)192 * K;

  // fragment-read swizzled slot offsets (row&7 == ln&7 for all frag rows)
  int sw0 = (kg ^ (ln & 7)) * 8;        // ks=0
  int sw1 = ((4 + kg) ^ (ln & 7)) * 8;  // ks=1
  int arow = wr * 64 + ln;
  int brow = wc * 64 + ln;

  f32x4 acc[4][4] = {};

  // prologue: stage tile 0 into buffer 0
  gl_lds16(pA0, &As[0][tid * 8]);
  gl_lds16(pA1, &As[0][4096 + tid * 8]);
  gl_lds16(pB0, &Bs[0][tid * 8]);
  gl_lds16(pB1, &Bs[0][4096 + tid * 8]);
  gl_lds16(pB2, &Bs[0][8192 + tid * 8]);
  gl_lds16(pB3, &Bs[0][12288 + tid * 8]);
  __syncthreads();

  for (int t = 0; t < NT; ++t) {
    int cur = t & 1, nb = cur ^ 1;
    int ko = (t + 1) * 64;
    bool more = (t + 1) < NT;
    const unsigned short* Ac = As[cur];
    const unsigned short* Bc = Bs[cur];
    bf16x8 a[4], b0, b1;

    // ---- phase 0: ks=0, n=0,1 ----
#pragma unroll
    for (int m = 0; m < 4; ++m) a[m] = *(const bf16x8*)&Ac[(arow + m * 16) * 64 + sw0];
    b0 = *(const bf16x8*)&Bc[(brow + 0) * 64 + sw0];
    b1 = *(const bf16x8*)&Bc[(brow + 16) * 64 + sw0];
    if (more) { gl_lds16(pA0 + ko, &As[nb][tid * 8]); gl_lds16(pB0 + ko, &Bs[nb][tid * 8]); }
    __builtin_amdgcn_s_setprio(1);
#pragma unroll
    for (int m = 0; m < 4; ++m) {
      acc[m][0] = __builtin_amdgcn_mfma_f32_16x16x32_bf16(a[m], b0, acc[m][0], 0, 0, 0);
      acc[m][1] = __builtin_amdgcn_mfma_f32_16x16x32_bf16(a[m], b1, acc[m][1], 0, 0, 0);
    }
    __builtin_amdgcn_s_setprio(0);

    // ---- phase 1: ks=0, n=2,3 ----
    b0 = *(const bf16x8*)&Bc[(brow + 32) * 64 + sw0];
    b1 = *(const bf16x8*)&Bc[(brow + 48) * 64 + sw0];
    if (more) { gl_lds16(pA1 + ko, &As[nb][4096 + tid * 8]); gl_lds16(pB1 + ko, &Bs[nb][4096 + tid * 8]); }
    __builtin_amdgcn_s_setprio(1);
#pragma unroll
    for (int m = 0; m < 4; ++m) {
      acc[m][2] = __builtin_amdgcn_mfma_f32_16x16x32_bf16(a[m], b0, acc[m][2], 0, 0, 0);
      acc[m][3] = __builtin_amdgcn_mfma_f32_16x16x32_bf16(a[m], b1, acc[m][3], 0, 0, 0);
    }
    __builtin_amdgcn_s_setprio(0);

    // ---- phase 2: ks=1, n=0,1 ----
#pragma unroll
    for (int m = 0; m < 4; ++m) a[m] = *(const bf16x8*)&Ac[(arow + m * 16) * 64 + sw1];
    b0 = *(const bf16x8*)&Bc[(brow + 0) * 64 + sw1];
    b1 = *(const bf16x8*)&Bc[(brow + 16) * 64 + sw1];
    if (more) gl_lds16(pB2 + ko, &Bs[nb][8192 + tid * 8]);
    __builtin_amdgcn_s_setprio(1);
#pragma unroll
    for (int m = 0; m < 4; ++m) {
      acc[m][0] = __builtin_amdgcn_mfma_f32_16x16x32_bf16(a[m], b0, acc[m][0], 0, 0, 0);
      acc[m][1] = __builtin_amdgcn_mfma_f32_16x16x32_bf16(a[m], b1, acc[m][1], 0, 0, 0);
    }
    __builtin_amdgcn_s_setprio(0);

    // ---- phase 3: ks=1, n=2,3 ----
    b0 = *(const bf16x8*)&Bc[(brow + 32) * 64 + sw1];
    b1 = *(const bf16x8*)&Bc[(brow + 48) * 64 + sw1];
    if (more) gl_lds16(pB3 + ko, &Bs[nb][12288 + tid * 8]);
    __builtin_amdgcn_s_setprio(1);
#pragma unroll
    for (int m = 0; m < 4; ++m) {
      acc[m][2] = __builtin_amdgcn_mfma_f32_16x16x32_bf16(a[m], b0, acc[m][2], 0, 0, 0);
      acc[m][3] = __builtin_amdgcn_mfma_f32_16x16x32_bf16(a[m], b1, acc[m][3], 0, 0, 0);
    }
    __builtin_amdgcn_s_setprio(0);

    __syncthreads();  // drains vmcnt (tile t+1 loads landed) + WAR protection
  }

  // ---- epilogue ----
  int mat = bn >> 3;  // which 2048-col output matrix (Q/K/V fusion); 0 for out-proj
  size_t cbase = (size_t)mat * 8388608 + (size_t)((bn & 7) * 256 + wc * 64 + ln);
#pragma unroll
  for (int m = 0; m < 4; ++m)
#pragma unroll
    for (int j = 0; j < 4; ++j) {
      size_t r = (size_t)(m0 + wr * 64 + m * 16 + kg * 4 + j) * 2048 + cbase;
#pragma unroll
      for (int n = 0; n < 4; ++n) {
        float v = acc[m][n][j];
        if (OUT_F32)
          ((float*)C)[r + n * 16] = v;
        else
          ((unsigned short*)C)[r + n * 16] = f2b(v);
      }
    }
}

// ---------- flash attention v3 (unchanged from round 3) ----------
__global__ __launch_bounds__(256, 2) void attn3_kernel(const unsigned short* __restrict__ Qb,
                                                       const unsigned short* __restrict__ Kb,
                                                       const unsigned short* __restrict__ Vt,
                                                       unsigned short* __restrict__ Ob) {
  __shared__ unsigned short KS[2][8192];
  __shared__ unsigned short VS[2][8192];
  __shared__ unsigned short PS[4][2048];
  const int D = 2048, L = 2048;
  int tid = threadIdx.x, lane = tid & 63, w = tid >> 6;
  int ln = lane & 15, kg = lane >> 4;
  int bid = blockIdx.x;
  int g = bid >> 5, bh = bid & 31;
  int qt = (g < 8) ? (15 - g) : (g - 8);
  int b = bh >> 4, h = bh & 15;
  const size_t base = (size_t)b * L * D + h * 128;
  const unsigned short* Kp = Kb + base;
  const unsigned short* Qp = Qb + base;
  unsigned short* Op = Ob + base;
  const unsigned short* Vp = Vt + (size_t)bh * 128 * L;

  int q0 = qt * 128;
  int qw0 = q0 + w * 32;

  bf16x8 aq[2][4];
#pragma unroll
  for (int m = 0; m < 2; ++m)
#pragma unroll
    for (int kc = 0; kc < 4; ++kc)
      aq[m][kc] = *(const bf16x8*)&Qp[(size_t)(qw0 + m * 16 + ln) * D + kc * 32 + kg * 8];

  f32x4 o[2][8] = {};
  float m2[2][4], ls[2][4];
#pragma unroll
  for (int m = 0; m < 2; ++m)
#pragma unroll
    for (int j = 0; j < 4; ++j) { m2[m][j] = -1e30f; ls[m][j] = 0.f; }

  int l16 = lane >> 4, l8 = lane >> 3, l7 = lane & 7;

#define STAGE(T, NB)                                                                   \
  {                                                                                    \
    int kv0_ = (T) << 6;                                                               \
    _Pragma("unroll") for (int i = 0; i < 4; ++i) {                                    \
      int cK = w * 4 + i;                                                              \
      int r = cK * 4 + l16;                                                            \
      int sw = ln ^ (r & 7);                                                           \
      gl_lds16(Kp + (size_t)(kv0_ + r) * D + sw * 8, &KS[NB][cK * 512 + lane * 8]);    \
      int dh = cK * 8 + l8;                                                            \
      int sv = l7 ^ (dh & 7);                                                          \
      gl_lds16(Vp + (size_t)dh * L + kv0_ + sv * 8, &VS[NB][cK * 512 + lane * 8]);     \
    }                                                                                  \
  }

  int nt = 2 * qt + 2;
  int mask_t = 2 * qt + (w >> 1);

  STAGE(0, 0);
  __syncthreads();

  for (int t = 0; t < nt; ++t) {
    int cur = t & 1;
    if (t + 1 < nt) STAGE(t + 1, cur ^ 1);

    if (t <= mask_t) {
      int kv0 = t << 6;
      f32x4 s[2][4] = {};
#pragma unroll
      for (int n = 0; n < 4; ++n)
#pragma unroll
        for (int kc = 0; kc < 4; ++kc) {
          bf16x8 bk = *(const bf16x8*)&KS[cur][(n * 16 + ln) * 128 + (((kc << 2) + kg) ^ (ln & 7)) * 8];
          s[0][n] = __builtin_amdgcn_mfma_f32_16x16x32_bf16(aq[0][kc], bk, s[0][n], 0, 0, 0);
          s[1][n] = __builtin_amdgcn_mfma_f32_16x16x32_bf16(aq[1][kc], bk, s[1][n], 0, 0, 0);
        }
      if (t == mask_t) {
#pragma unroll
        for (int m = 0; m < 2; ++m)
#pragma unroll
          for (int n = 0; n < 4; ++n)
#pragma unroll
            for (int j = 0; j < 4; ++j)
              if (kv0 + n * 16 + ln > qw0 + m * 16 + kg * 4 + j) s[m][n][j] = -1e30f;
      }
      float pmax[2][4];
      bool near = true;
#pragma unroll
      for (int m = 0; m < 2; ++m)
#pragma unroll
        for (int j = 0; j < 4; ++j) {
          pmax[m][j] = fmaxf(fmaxf(s[m][0][j], s[m][1][j]), fmaxf(s[m][2][j], s[m][3][j]));
          near = near && (pmax[m][j] <= m2[m][j] + 8.0f);
        }
      if (!__all(near)) {
#pragma unroll
        for (int m = 0; m < 2; ++m)
#pragma unroll
          for (int j = 0; j < 4; ++j) {
            float mx = pmax[m][j];
#pragma unroll
            for (int d = 1; d < 16; d <<= 1) mx = fmaxf(mx, __shfl_xor(mx, d));
            mx = fmaxf(mx, m2[m][j]);
            float al = __builtin_amdgcn_exp2f(m2[m][j] - mx);
            m2[m][j] = mx;
            ls[m][j] *= al;
#pragma unroll
            for (int dt = 0; dt < 8; ++dt) o[m][dt][j] *= al;
          }
      }
#pragma unroll
      for (int m = 0; m < 2; ++m)
#pragma unroll
        for (int j = 0; j < 4; ++j) {
          int row = m * 16 + kg * 4 + j;
          float acc = 0.f;
#pragma unroll
          for (int n = 0; n < 4; ++n) {
            float p = __builtin_amdgcn_exp2f(s[m][n][j] - m2[m][j]);
            acc += p;
            unsigned int u = __builtin_bit_cast(unsigned int, p);
            PS[w][row * 64 + (((n * 2 + (ln >> 3)) ^ (row & 7)) * 8) + (ln & 7)] =
                (unsigned short)(u >> 16);
          }
          ls[m][j] += acc;
        }
#pragma unroll
      for (int kst = 0; kst < 2; ++kst) {
        bf16x8 ap0 = *(const bf16x8*)&PS[w][(ln) * 64 + (((kst << 2) + kg) ^ (ln & 7)) * 8];
        bf16x8 ap1 = *(const bf16x8*)&PS[w][(16 + ln) * 64 + (((kst << 2) + kg) ^ (ln & 7)) * 8];
#pragma unroll
        for (int dt = 0; dt < 8; ++dt) {
          bf16x8 bv = *(const bf16x8*)&VS[cur][(dt * 16 + ln) * 64 + (((kst << 2) + kg) ^ (ln & 7)) * 8];
          o[0][dt] = __builtin_amdgcn_mfma_f32_16x16x32_bf16(ap0, bv, o[0][dt], 0, 0, 0);
          o[1][dt] = __builtin_amdgcn_mfma_f32_16x16x32_bf16(ap1, bv, o[1][dt], 0, 0, 0);
        }
      }
    }
    __syncthreads();
  }
#undef STAGE

#pragma unroll
  for (int m = 0; m < 2; ++m)
#pragma unroll
    for (int j = 0; j < 4; ++j) {
      float tsum = ls[m][j];
#pragma unroll
      for (int d = 1; d < 16; d <<= 1) tsum += __shfl_xor(tsum, d);
      float inv = 1.0f / tsum;
      int row = qw0 + m * 16 + kg * 4 + j;
#pragma unroll
      for (int dt = 0; dt < 8; ++dt)
        Op[(size_t)row * D + dt * 16 + ln] = f2b(o[m][dt][j] * inv);
    }
}

// ---------- launch ----------
extern "C" void kernel_launch(void* const* d_in, const int* in_sizes, int n_in,
                              void* d_out, int out_size, void* d_ws, size_t ws_size,
                              hipStream_t stream) {
  const float* x  = (const float*)d_in[0];
  // d_in[1] = mask (causal; applied analytically)
  const float* Wq = (const float*)d_in[2];
  const float* Wk = (const float*)d_in[3];
  const float* Wv = (const float*)d_in[4];
  const float* Wo = (const float*)d_in[5];

  char* ws = (char*)d_ws;
  unsigned short* xb  = (unsigned short*)(ws + 0);
  unsigned short* wqb = (unsigned short*)(ws + 16777216);  // wq|wk|wv contiguous = [6144][2048]
  unsigned short* wkb = (unsigned short*)(ws + 25165824);
  unsigned short* wvb = (unsigned short*)(ws + 33554432);
  unsigned short* wob = (unsigned short*)(ws + 41943040);
  unsigned short* qb  = (unsigned short*)(ws + 50331648);  // q|k|v contiguous outputs
  unsigned short* kb  = (unsigned short*)(ws + 67108864);
  unsigned short* vb  = (unsigned short*)(ws + 83886080);
  float2* tab         = (float2*)(ws + 100663296);
  unsigned short* vt  = wqb;  // reuse wq+wk region after fused QKV GEMM
  unsigned short* ob  = xb;

  float* out  = (float*)d_out;
  float* kout = out + 8388608;
  float* vout = out + 16777216;

  cast_kernel<<<8192, 256, 0, stream>>>(x, xb, 2097152);
  cast4_kernel<<<dim3(4096, 4), 256, 0, stream>>>(Wq, Wk, Wv, Wo, wqb, wkb, wvb, wob, 1048576);
  rope_table_kernel<<<512, 256, 0, stream>>>(tab);

  // fused QKV GEMM: [4096x2048] x [6144x2048]^T -> q|k|v
  gemm2<24, 0><<<768, 512, 0, stream>>>(xb, wqb, qb);

  transpose_v_kernel<<<dim3(64, 4, 32), 256, 0, stream>>>(vb, vt);

  rope_apply_kernel<<<dim3(16384, 3), 256, 0, stream>>>(qb, kb, vb, kout, vout, tab);

  attn3_kernel<<<512, 256, 0, stream>>>(qb, kb, vt, ob);

  // output projection
  gemm2<8, 1><<<256, 512, 0, stream>>>(ob, wob, out);
}

// Round 5
// 327.930 us; speedup vs baseline: 1.0805x; 1.0805x over previous
//
#include <hip/hip_runtime.h>

// ---------- types / helpers ----------
typedef __attribute__((ext_vector_type(4))) float f32x4;
typedef __attribute__((ext_vector_type(8))) __bf16 bf16x8;

__device__ __forceinline__ unsigned short f2b(float f) {
  unsigned int u = __builtin_bit_cast(unsigned int, f);
  u = (u + 0x7fffu + ((u >> 16) & 1u)) >> 16;
  return (unsigned short)u;
}
__device__ __forceinline__ float b2f(unsigned short h) {
  unsigned int u = ((unsigned int)h) << 16;
  return __builtin_bit_cast(float, u);
}
__device__ __forceinline__ void gl_lds16(const void* g, void* l) {
  __builtin_amdgcn_global_load_lds(
      (const __attribute__((address_space(1))) void*)g,
      (__attribute__((address_space(3))) void*)l, 16, 0, 0);
}

// ---------- fp32 -> bf16 cast ----------
__global__ void cast_kernel(const float* __restrict__ src,
                            unsigned short* __restrict__ dst, int n4) {
  int i = blockIdx.x * blockDim.x + threadIdx.x;
  if (i >= n4) return;
  float4 v = ((const float4*)src)[i];
  ushort4 o;
  o.x = f2b(v.x); o.y = f2b(v.y); o.z = f2b(v.z); o.w = f2b(v.w);
  ((ushort4*)dst)[i] = o;
}

__global__ void cast4_kernel(const float* __restrict__ s0, const float* __restrict__ s1,
                             const float* __restrict__ s2, const float* __restrict__ s3,
                             unsigned short* __restrict__ d0, unsigned short* __restrict__ d1,
                             unsigned short* __restrict__ d2, unsigned short* __restrict__ d3,
                             int n4) {
  int i = blockIdx.x * blockDim.x + threadIdx.x;
  if (i >= n4) return;
  const float* src = blockIdx.y == 0 ? s0 : blockIdx.y == 1 ? s1 : blockIdx.y == 2 ? s2 : s3;
  unsigned short* dst = blockIdx.y == 0 ? d0 : blockIdx.y == 1 ? d1 : blockIdx.y == 2 ? d2 : d3;
  float4 v = ((const float4*)src)[i];
  ushort4 o;
  o.x = f2b(v.x); o.y = f2b(v.y); o.z = f2b(v.z); o.w = f2b(v.w);
  ((ushort4*)dst)[i] = o;
}

// ---------- RoPE cos/sin table ----------
__global__ void rope_table_kernel(float2* __restrict__ tab) {
  int idx = blockIdx.x * blockDim.x + threadIdx.x;
  int l = idx >> 6, i = idx & 63;
  float freq = powf(10000.0f, -(float)(2 * i) / 128.0f);
  float th = (float)l * freq;
  tab[idx] = make_float2(cosf(th), sinf(th));
}

// ---------- RoPE apply; q additionally pre-scaled by 1/sqrt(Dh)*log2(e) ----------
__global__ void rope_apply_kernel(unsigned short* __restrict__ qb,
                                  unsigned short* __restrict__ kb,
                                  unsigned short* __restrict__ vb,
                                  float* __restrict__ kout,
                                  float* __restrict__ vout,
                                  const float2* __restrict__ tab) {
  const float QS = 0.12751743f;  // (1/sqrt(128)) * log2(e)
  int z = blockIdx.y;
  int p = blockIdx.x * blockDim.x + threadIdx.x;
  int i = p & 63;
  int t = p >> 6;
  int h = t & 15; t >>= 4;
  int l = t & 2047;
  int b = t >> 11;
  int base = ((b * 2048 + l) * 2048) + h * 128 + 2 * i;
  int obase = ((b * 16 + h) * 2048 + l) * 128 + 2 * i;
  if (z == 2) {
    vout[obase] = b2f(vb[base]);
    vout[obase + 1] = b2f(vb[base + 1]);
  } else {
    unsigned short* buf = z ? kb : qb;
    float x1 = b2f(buf[base]), x2 = b2f(buf[base + 1]);
    float2 cs = tab[l * 64 + i];
    float r1 = x1 * cs.x - x2 * cs.y;
    float r2 = x1 * cs.y + x2 * cs.x;
    if (z == 1) {
      buf[base] = f2b(r1);
      buf[base + 1] = f2b(r2);
      kout[obase] = r1; kout[obase + 1] = r2;
    } else {
      buf[base] = f2b(r1 * QS);
      buf[base + 1] = f2b(r2 * QS);
    }
  }
}

// ---------- tiled transpose: vb (B,L,D) head-slice -> vt (B,H,Dh,L) ----------
__global__ __launch_bounds__(256) void transpose_v_kernel(const unsigned short* __restrict__ vb,
                                                          unsigned short* __restrict__ vt) {
  __shared__ unsigned short t[32][33];
  int bz = blockIdx.z;
  int b = bz >> 4, h = bz & 15;
  int l0 = blockIdx.x * 32, d0 = blockIdx.y * 32;
  const unsigned short* src = vb + (size_t)b * 2048 * 2048 + h * 128;
  unsigned short* dst = vt + (size_t)bz * 128 * 2048;
  int tx = threadIdx.x & 31, ty = threadIdx.x >> 5;
#pragma unroll
  for (int i = 0; i < 4; ++i)
    t[ty + 8 * i][tx] = src[(size_t)(l0 + ty + 8 * i) * 2048 + d0 + tx];
  __syncthreads();
#pragma unroll
  for (int i = 0; i < 4; ++i)
    dst[(size_t)(d0 + ty + 8 * i) * 2048 + l0 + tx] = t[tx][ty + 8 * i];
}

// ---------- GEMM v3: 8-phase schedule, counted vmcnt (T2+T3+T4+T5+T1) ----------
// C = A[4096xK] * W[(NBN*256)xK]^T, BK=64, 8 waves (2M x 4N), BM in {128,256}, BN=256.
// LDS: Asm[dbuf][half][AH x 64], Bsm[dbuf][half][128 x 64], XOR-swizzled (slot ^= row&7).
// Half-tile staging 1/phase, raw s_barrier, vmcnt(4|3) at phases 4 & 8 only.
template <int BM, int NBN, int OUT_F32>
__global__ __launch_bounds__(512, 2) void gemm3(const unsigned short* __restrict__ A,
                                                const unsigned short* __restrict__ W,
                                                void* __restrict__ C) {
  constexpr int K = 2048, NT = 32;   // 32 K-tiles of 64
  constexpr int AH = BM / 2;         // rows per A-half
  constexpr int MF = BM / 64;        // M-frags per quadrant
  constexpr int AQ = AH / 64;        // gl_lds per thread per A-half
  __shared__ unsigned short Asm[2][2][AH * 64];
  __shared__ unsigned short Bsm[2][2][128 * 64];

  const int tid = threadIdx.x, lane = tid & 63, wv = tid >> 6;
  const int wr = wv >> 2, wc = wv & 3;
  const int ln = lane & 15, kg = lane >> 4;

  const int cpx = (int)gridDim.x >> 3;
  const int swzb = ((int)blockIdx.x & 7) * cpx + ((int)blockIdx.x >> 3);
  const int bm = swzb / NBN, bn = swzb % NBN;
  const int m0 = bm * BM, n0 = bn * 256;

  // staging source (pre-swizzled global address; LDS dest linear)
  const int rr = lane >> 3;
  const int sws = ((lane & 7) ^ (rr & 7)) * 8;
  const unsigned short* pA = A + (size_t)(m0 + wv * 8 * AQ + rr) * K + sws;
  const unsigned short* pB = W + (size_t)(n0 + wv * 16 + rr) * K + sws;

#define STA_(dd, hh, tt)                                                         \
  _Pragma("unroll") for (int q = 0; q < AQ; ++q)                                 \
      gl_lds16(pA + ((size_t)(hh)*AH + q * 8) * K + (size_t)(tt)*64,             \
               &Asm[dd][hh][(wv * 8 * AQ + q * 8) * 64 + lane * 8]);
#define STB_(dd, hh, tt)                                                         \
  _Pragma("unroll") for (int q = 0; q < 2; ++q)                                  \
      gl_lds16(pB + ((size_t)(hh)*128 + q * 8) * K + (size_t)(tt)*64,            \
               &Bsm[dd][hh][(wv * 16 + q * 8) * 64 + lane * 8]);

  const int sw0 = (kg ^ (ln & 7)) * 8;
  const int sw1 = ((4 + kg) ^ (ln & 7)) * 8;
  const int rae = (wr * (AH / 2) + ln) * 64;
  const int rbe = (wc * 32 + ln) * 64;

  f32x4 acc[2 * MF][4] = {};
  bf16x8 aA[MF][2], bB[2][2];

#define QUAD(dd, mh, bh, LA, LB)                                                  \
  {                                                                               \
    if (LA) {                                                                     \
      _Pragma("unroll") for (int mf = 0; mf < MF; ++mf) {                         \
        aA[mf][0] = *(const bf16x8*)&Asm[dd][mh][rae + mf * 1024 + sw0];          \
        aA[mf][1] = *(const bf16x8*)&Asm[dd][mh][rae + mf * 1024 + sw1];          \
      }                                                                           \
    }                                                                             \
    if (LB) {                                                                     \
      _Pragma("unroll") for (int nf = 0; nf < 2; ++nf) {                          \
        bB[nf][0] = *(const bf16x8*)&Bsm[dd][bh][rbe + nf * 1024 + sw0];          \
        bB[nf][1] = *(const bf16x8*)&Bsm[dd][bh][rbe + nf * 1024 + sw1];          \
      }                                                                           \
    }                                                                             \
    __builtin_amdgcn_s_setprio(1);                                                \
    _Pragma("unroll") for (int mf = 0; mf < MF; ++mf)                             \
        _Pragma("unroll") for (int nf = 0; nf < 2; ++nf) {                        \
      acc[(mh)*MF + mf][(bh)*2 + nf] = __builtin_amdgcn_mfma_f32_16x16x32_bf16(   \
          aA[mf][0], bB[nf][0], acc[(mh)*MF + mf][(bh)*2 + nf], 0, 0, 0);         \
      acc[(mh)*MF + mf][(bh)*2 + nf] = __builtin_amdgcn_mfma_f32_16x16x32_bf16(   \
          aA[mf][1], bB[nf][1], acc[(mh)*MF + mf][(bh)*2 + nf], 0, 0, 0);         \
    }                                                                             \
    __builtin_amdgcn_s_setprio(0);                                                \
  }

#define BAR                                                                       \
  __builtin_amdgcn_s_barrier();                                                   \
  __builtin_amdgcn_sched_barrier(0);
#define VWAIT                                                                     \
  if (BM == 256) { asm volatile("s_waitcnt vmcnt(4)" ::: "memory"); }             \
  else { asm volatile("s_waitcnt vmcnt(3)" ::: "memory"); }

  // prologue: tile0 (a0,b0,b1,a1) complete; tile1 (a0,b1) partial
  STA_(0, 0, 0); STB_(0, 0, 0); STB_(0, 1, 0); STA_(0, 1, 0);
  STA_(1, 0, 1); STB_(1, 1, 1);
  VWAIT; BAR;

  for (int T = 0; T < NT; T += 2) {
    const bool more = (T + 2) < NT;
    // p1..p4: compute tile T (dbuf 0)
    STB_(1, 0, T + 1);            QUAD(0, 0, 0, 1, 1); BAR;
    STA_(1, 1, T + 1);            QUAD(0, 0, 1, 0, 1); BAR;
    if (more) STA_(0, 0, T + 2);  QUAD(0, 1, 1, 1, 0); BAR;
    if (more) STB_(0, 1, T + 2);  QUAD(0, 1, 0, 0, 1);
    if (more) { VWAIT; } else { asm volatile("s_waitcnt vmcnt(0)" ::: "memory"); }
    BAR;
    // p5..p8: compute tile T+1 (dbuf 1)
    if (more) STB_(0, 0, T + 2);  QUAD(1, 0, 0, 1, 1); BAR;
    if (more) STA_(0, 1, T + 2);  QUAD(1, 0, 1, 0, 1); BAR;
    if (more) STA_(1, 0, T + 3);  QUAD(1, 1, 1, 1, 0); BAR;
    if (more) {
      STB_(1, 1, T + 3);          QUAD(1, 1, 0, 0, 1); VWAIT; BAR;
    } else {
      QUAD(1, 1, 0, 0, 1);
    }
  }

  // epilogue
  const int mat = bn >> 3;
  unsigned short* Cb = (unsigned short*)C;
  float* Cf = (float*)C;
#pragma unroll
  for (int mh = 0; mh < 2; ++mh)
#pragma unroll
    for (int mf = 0; mf < MF; ++mf)
#pragma unroll
      for (int j = 0; j < 4; ++j) {
        int row = m0 + mh * AH + wr * (AH / 2) + mf * 16 + kg * 4 + j;
        size_t rb = (size_t)mat * 8388608 + (size_t)row * 2048 + (size_t)((bn & 7) * 256);
#pragma unroll
        for (int bh = 0; bh < 2; ++bh)
#pragma unroll
          for (int nf = 0; nf < 2; ++nf) {
            int col = bh * 128 + wc * 32 + nf * 16 + ln;
            float v = acc[mh * MF + mf][bh * 2 + nf][j];
            if (OUT_F32) Cf[rb + col] = v;
            else Cb[rb + col] = f2b(v);
          }
      }
#undef STA_
#undef STB_
#undef QUAD
#undef BAR
#undef VWAIT
}

// ---------- flash attention v3 (unchanged from round 3) ----------
__global__ __launch_bounds__(256, 2) void attn3_kernel(const unsigned short* __restrict__ Qb,
                                                       const unsigned short* __restrict__ Kb,
                                                       const unsigned short* __restrict__ Vt,
                                                       unsigned short* __restrict__ Ob) {
  __shared__ unsigned short KS[2][8192];
  __shared__ unsigned short VS[2][8192];
  __shared__ unsigned short PS[4][2048];
  const int D = 2048, L = 2048;
  int tid = threadIdx.x, lane = tid & 63, w = tid >> 6;
  int ln = lane & 15, kg = lane >> 4;
  int bid = blockIdx.x;
  int g = bid >> 5, bh = bid & 31;
  int qt = (g < 8) ? (15 - g) : (g - 8);
  int b = bh >> 4, h = bh & 15;
  const size_t base = (size_t)b * L * D + h * 128;
  const unsigned short* Kp = Kb + base;
  const unsigned short* Qp = Qb + base;
  unsigned short* Op = Ob + base;
  const unsigned short* Vp = Vt + (size_t)bh * 128 * L;

  int q0 = qt * 128;
  int qw0 = q0 + w * 32;

  bf16x8 aq[2][4];
#pragma unroll
  for (int m = 0; m < 2; ++m)
#pragma unroll
    for (int kc = 0; kc < 4; ++kc)
      aq[m][kc] = *(const bf16x8*)&Qp[(size_t)(qw0 + m * 16 + ln) * D + kc * 32 + kg * 8];

  f32x4 o[2][8] = {};
  float m2[2][4], ls[2][4];
#pragma unroll
  for (int m = 0; m < 2; ++m)
#pragma unroll
    for (int j = 0; j < 4; ++j) { m2[m][j] = -1e30f; ls[m][j] = 0.f; }

  int l16 = lane >> 4, l8 = lane >> 3, l7 = lane & 7;

#define STAGE(T, NB)                                                                   \
  {                                                                                    \
    int kv0_ = (T) << 6;                                                               \
    _Pragma("unroll") for (int i = 0; i < 4; ++i) {                                    \
      int cK = w * 4 + i;                                                              \
      int r = cK * 4 + l16;                                                            \
      int sw = ln ^ (r & 7);                                                           \
      gl_lds16(Kp + (size_t)(kv0_ + r) * D + sw * 8, &KS[NB][cK * 512 + lane * 8]);    \
      int dh = cK * 8 + l8;                                                            \
      int sv = l7 ^ (dh & 7);                                                          \
      gl_lds16(Vp + (size_t)dh * L + kv0_ + sv * 8, &VS[NB][cK * 512 + lane * 8]);     \
    }                                                                                  \
  }

  int nt = 2 * qt + 2;
  int mask_t = 2 * qt + (w >> 1);

  STAGE(0, 0);
  __syncthreads();

  for (int t = 0; t < nt; ++t) {
    int cur = t & 1;
    if (t + 1 < nt) STAGE(t + 1, cur ^ 1);

    if (t <= mask_t) {
      int kv0 = t << 6;
      f32x4 s[2][4] = {};
#pragma unroll
      for (int n = 0; n < 4; ++n)
#pragma unroll
        for (int kc = 0; kc < 4; ++kc) {
          bf16x8 bk = *(const bf16x8*)&KS[cur][(n * 16 + ln) * 128 + (((kc << 2) + kg) ^ (ln & 7)) * 8];
          s[0][n] = __builtin_amdgcn_mfma_f32_16x16x32_bf16(aq[0][kc], bk, s[0][n], 0, 0, 0);
          s[1][n] = __builtin_amdgcn_mfma_f32_16x16x32_bf16(aq[1][kc], bk, s[1][n], 0, 0, 0);
        }
      if (t == mask_t) {
#pragma unroll
        for (int m = 0; m < 2; ++m)
#pragma unroll
          for (int n = 0; n < 4; ++n)
#pragma unroll
            for (int j = 0; j < 4; ++j)
              if (kv0 + n * 16 + ln > qw0 + m * 16 + kg * 4 + j) s[m][n][j] = -1e30f;
      }
      float pmax[2][4];
      bool near = true;
#pragma unroll
      for (int m = 0; m < 2; ++m)
#pragma unroll
        for (int j = 0; j < 4; ++j) {
          pmax[m][j] = fmaxf(fmaxf(s[m][0][j], s[m][1][j]), fmaxf(s[m][2][j], s[m][3][j]));
          near = near && (pmax[m][j] <= m2[m][j] + 8.0f);
        }
      if (!__all(near)) {
#pragma unroll
        for (int m = 0; m < 2; ++m)
#pragma unroll
          for (int j = 0; j < 4; ++j) {
            float mx = pmax[m][j];
#pragma unroll
            for (int d = 1; d < 16; d <<= 1) mx = fmaxf(mx, __shfl_xor(mx, d));
            mx = fmaxf(mx, m2[m][j]);
            float al = __builtin_amdgcn_exp2f(m2[m][j] - mx);
            m2[m][j] = mx;
            ls[m][j] *= al;
#pragma unroll
            for (int dt = 0; dt < 8; ++dt) o[m][dt][j] *= al;
          }
      }
#pragma unroll
      for (int m = 0; m < 2; ++m)
#pragma unroll
        for (int j = 0; j < 4; ++j) {
          int row = m * 16 + kg * 4 + j;
          float acc = 0.f;
#pragma unroll
          for (int n = 0; n < 4; ++n) {
            float p = __builtin_amdgcn_exp2f(s[m][n][j] - m2[m][j]);
            acc += p;
            unsigned int u = __builtin_bit_cast(unsigned int, p);
            PS[w][row * 64 + (((n * 2 + (ln >> 3)) ^ (row & 7)) * 8) + (ln & 7)] =
                (unsigned short)(u >> 16);
          }
          ls[m][j] += acc;
        }
#pragma unroll
      for (int kst = 0; kst < 2; ++kst) {
        bf16x8 ap0 = *(const bf16x8*)&PS[w][(ln) * 64 + (((kst << 2) + kg) ^ (ln & 7)) * 8];
        bf16x8 ap1 = *(const bf16x8*)&PS[w][(16 + ln) * 64 + (((kst << 2) + kg) ^ (ln & 7)) * 8];
#pragma unroll
        for (int dt = 0; dt < 8; ++dt) {
          bf16x8 bv = *(const bf16x8*)&VS[cur][(dt * 16 + ln) * 64 + (((kst << 2) + kg) ^ (ln & 7)) * 8];
          o[0][dt] = __builtin_amdgcn_mfma_f32_16x16x32_bf16(ap0, bv, o[0][dt], 0, 0, 0);
          o[1][dt] = __builtin_amdgcn_mfma_f32_16x16x32_bf16(ap1, bv, o[1][dt], 0, 0, 0);
        }
      }
    }
    __syncthreads();
  }
#undef STAGE

#pragma unroll
  for (int m = 0; m < 2; ++m)
#pragma unroll
    for (int j = 0; j < 4; ++j) {
      float tsum = ls[m][j];
#pragma unroll
      for (int d = 1; d < 16; d <<= 1) tsum += __shfl_xor(tsum, d);
      float inv = 1.0f / tsum;
      int row = qw0 + m * 16 + kg * 4 + j;
#pragma unroll
      for (int dt = 0; dt < 8; ++dt)
        Op[(size_t)row * D + dt * 16 + ln] = f2b(o[m][dt][j] * inv);
    }
}

// ---------- launch ----------
extern "C" void kernel_launch(void* const* d_in, const int* in_sizes, int n_in,
                              void* d_out, int out_size, void* d_ws, size_t ws_size,
                              hipStream_t stream) {
  const float* x  = (const float*)d_in[0];
  // d_in[1] = mask (causal; applied analytically)
  const float* Wq = (const float*)d_in[2];
  const float* Wk = (const float*)d_in[3];
  const float* Wv = (const float*)d_in[4];
  const float* Wo = (const float*)d_in[5];

  char* ws = (char*)d_ws;
  unsigned short* xb  = (unsigned short*)(ws + 0);
  unsigned short* wqb = (unsigned short*)(ws + 16777216);  // wq|wk|wv contiguous = [6144][2048]
  unsigned short* wkb = (unsigned short*)(ws + 25165824);
  unsigned short* wvb = (unsigned short*)(ws + 33554432);
  unsigned short* wob = (unsigned short*)(ws + 41943040);
  unsigned short* qb  = (unsigned short*)(ws + 50331648);  // q|k|v contiguous outputs
  unsigned short* kb  = (unsigned short*)(ws + 67108864);
  unsigned short* vb  = (unsigned short*)(ws + 83886080);
  float2* tab         = (float2*)(ws + 100663296);
  unsigned short* vt  = wqb;  // reuse wq+wk region after QKV GEMM
  unsigned short* ob  = xb;

  float* out  = (float*)d_out;
  float* kout = out + 8388608;
  float* vout = out + 16777216;

  cast_kernel<<<8192, 256, 0, stream>>>(x, xb, 2097152);
  cast4_kernel<<<dim3(4096, 4), 256, 0, stream>>>(Wq, Wk, Wv, Wo, wqb, wkb, wvb, wob, 1048576);
  rope_table_kernel<<<512, 256, 0, stream>>>(tab);

  // fused QKV GEMM: [4096x2048] x [6144x2048]^T -> q|k|v  (384 blocks, BM=256)
  gemm3<256, 24, 0><<<384, 512, 0, stream>>>(xb, wqb, qb);

  transpose_v_kernel<<<dim3(64, 4, 32), 256, 0, stream>>>(vb, vt);

  rope_apply_kernel<<<dim3(16384, 3), 256, 0, stream>>>(qb, kb, vb, kout, vout, tab);

  attn3_kernel<<<512, 256, 0, stream>>>(qb, kb, vt, ob);

  // output projection (256 blocks, BM=128)
  gemm3<128, 8, 1><<<256, 512, 0, stream>>>(ob, wob, out);
}

// Round 6
// 306.559 us; speedup vs baseline: 1.1558x; 1.0697x over previous
//
#include <hip/hip_runtime.h>

// ---------- types / helpers ----------
typedef __attribute__((ext_vector_type(4))) float f32x4;
typedef __attribute__((ext_vector_type(8))) __bf16 bf16x8;

__device__ __forceinline__ unsigned short f2b(float f) {
  unsigned int u = __builtin_bit_cast(unsigned int, f);
  u = (u + 0x7fffu + ((u >> 16) & 1u)) >> 16;
  return (unsigned short)u;
}
__device__ __forceinline__ float b2f(unsigned short h) {
  unsigned int u = ((unsigned int)h) << 16;
  return __builtin_bit_cast(float, u);
}
__device__ __forceinline__ void gl_lds16(const void* g, void* l) {
  __builtin_amdgcn_global_load_lds(
      (const __attribute__((address_space(1))) void*)g,
      (__attribute__((address_space(3))) void*)l, 16, 0, 0);
}

// ---------- fp32 -> bf16 cast ----------
__global__ void cast_kernel(const float* __restrict__ src,
                            unsigned short* __restrict__ dst, int n4) {
  int i = blockIdx.x * blockDim.x + threadIdx.x;
  if (i >= n4) return;
  float4 v = ((const float4*)src)[i];
  ushort4 o;
  o.x = f2b(v.x); o.y = f2b(v.y); o.z = f2b(v.z); o.w = f2b(v.w);
  ((ushort4*)dst)[i] = o;
}

__global__ void cast4_kernel(const float* __restrict__ s0, const float* __restrict__ s1,
                             const float* __restrict__ s2, const float* __restrict__ s3,
                             unsigned short* __restrict__ d0, unsigned short* __restrict__ d1,
                             unsigned short* __restrict__ d2, unsigned short* __restrict__ d3,
                             int n4) {
  int i = blockIdx.x * blockDim.x + threadIdx.x;
  if (i >= n4) return;
  const float* src = blockIdx.y == 0 ? s0 : blockIdx.y == 1 ? s1 : blockIdx.y == 2 ? s2 : s3;
  unsigned short* dst = blockIdx.y == 0 ? d0 : blockIdx.y == 1 ? d1 : blockIdx.y == 2 ? d2 : d3;
  float4 v = ((const float4*)src)[i];
  ushort4 o;
  o.x = f2b(v.x); o.y = f2b(v.y); o.z = f2b(v.z); o.w = f2b(v.w);
  ((ushort4*)dst)[i] = o;
}

// ---------- RoPE cos/sin table ----------
__global__ void rope_table_kernel(float2* __restrict__ tab) {
  int idx = blockIdx.x * blockDim.x + threadIdx.x;
  int l = idx >> 6, i = idx & 63;
  float freq = powf(10000.0f, -(float)(2 * i) / 128.0f);
  float th = (float)l * freq;
  tab[idx] = make_float2(cosf(th), sinf(th));
}

// ---------- RoPE apply; q additionally pre-scaled by 1/sqrt(Dh)*log2(e) ----------
__global__ void rope_apply_kernel(unsigned short* __restrict__ qb,
                                  unsigned short* __restrict__ kb,
                                  unsigned short* __restrict__ vb,
                                  float* __restrict__ kout,
                                  float* __restrict__ vout,
                                  const float2* __restrict__ tab) {
  const float QS = 0.12751743f;  // (1/sqrt(128)) * log2(e)
  int z = blockIdx.y;
  int p = blockIdx.x * blockDim.x + threadIdx.x;
  int i = p & 63;
  int t = p >> 6;
  int h = t & 15; t >>= 4;
  int l = t & 2047;
  int b = t >> 11;
  int base = ((b * 2048 + l) * 2048) + h * 128 + 2 * i;
  int obase = ((b * 16 + h) * 2048 + l) * 128 + 2 * i;
  if (z == 2) {
    vout[obase] = b2f(vb[base]);
    vout[obase + 1] = b2f(vb[base + 1]);
  } else {
    unsigned short* buf = z ? kb : qb;
    float x1 = b2f(buf[base]), x2 = b2f(buf[base + 1]);
    float2 cs = tab[l * 64 + i];
    float r1 = x1 * cs.x - x2 * cs.y;
    float r2 = x1 * cs.y + x2 * cs.x;
    if (z == 1) {
      buf[base] = f2b(r1);
      buf[base + 1] = f2b(r2);
      kout[obase] = r1; kout[obase + 1] = r2;
    } else {
      buf[base] = f2b(r1 * QS);
      buf[base + 1] = f2b(r2 * QS);
    }
  }
}

// ---------- tiled transpose: vb (B,L,D) head-slice -> vt (B,H,Dh,L) ----------
__global__ __launch_bounds__(256) void transpose_v_kernel(const unsigned short* __restrict__ vb,
                                                          unsigned short* __restrict__ vt) {
  __shared__ unsigned short t[32][33];
  int bz = blockIdx.z;
  int b = bz >> 4, h = bz & 15;
  int l0 = blockIdx.x * 32, d0 = blockIdx.y * 32;
  const unsigned short* src = vb + (size_t)b * 2048 * 2048 + h * 128;
  unsigned short* dst = vt + (size_t)bz * 128 * 2048;
  int tx = threadIdx.x & 31, ty = threadIdx.x >> 5;
#pragma unroll
  for (int i = 0; i < 4; ++i)
    t[ty + 8 * i][tx] = src[(size_t)(l0 + ty + 8 * i) * 2048 + d0 + tx];
  __syncthreads();
#pragma unroll
  for (int i = 0; i < 4; ++i)
    dst[(size_t)(d0 + ty + 8 * i) * 2048 + l0 + tx] = t[tx][ty + 8 * i];
}

// ---------- GEMM v4: m201-faithful 8-phase (ds_read pre-barrier, 2 barriers/phase) ----------
// C = A[4096xK] * W[(NBN*256)xK]^T, BK=64, 8 waves (2M x 4N), BN=256.
// LDS: Asm/Bsm [dbuf][half][rows x 64] XOR-swizzled; staging ledger identical to r5 (verified).
template <int BM, int NBN, int OUT_F32>
__global__ __launch_bounds__(512, 2) void gemm4(const unsigned short* __restrict__ A,
                                                const unsigned short* __restrict__ W,
                                                void* __restrict__ C) {
  constexpr int K = 2048, NT = 32;
  constexpr int AH = BM / 2;
  constexpr int MF = BM / 64;
  constexpr int AQ = AH / 64;
  __shared__ unsigned short Asm[2][2][AH * 64];
  __shared__ unsigned short Bsm[2][2][128 * 64];

  const int tid = threadIdx.x, lane = tid & 63, wv = tid >> 6;
  const int wr = wv >> 2, wc = wv & 3;
  const int ln = lane & 15, kg = lane >> 4;

  const int cpx = (int)gridDim.x >> 3;
  const int swzb = ((int)blockIdx.x & 7) * cpx + ((int)blockIdx.x >> 3);
  const int bm = swzb / NBN, bn = swzb % NBN;
  const int m0 = bm * BM, n0 = bn * 256;

  const int rr = lane >> 3;
  const int sws = ((lane & 7) ^ (rr & 7)) * 8;
  const unsigned short* pA = A + (size_t)(m0 + wv * 8 * AQ + rr) * K + sws;
  const unsigned short* pB = W + (size_t)(n0 + wv * 16 + rr) * K + sws;

#define STA_(dd, hh, tt)                                                         \
  { _Pragma("unroll") for (int q = 0; q < AQ; ++q)                               \
      gl_lds16(pA + ((size_t)(hh)*AH + q * 8) * K + (size_t)(tt)*64,             \
               &Asm[dd][hh][(wv * 8 * AQ + q * 8) * 64 + lane * 8]); }
#define STB_(dd, hh, tt)                                                         \
  { _Pragma("unroll") for (int q = 0; q < 2; ++q)                                \
      gl_lds16(pB + ((size_t)(hh)*128 + q * 8) * K + (size_t)(tt)*64,            \
               &Bsm[dd][hh][(wv * 16 + q * 8) * 64 + lane * 8]); }

  const int sw0 = (kg ^ (ln & 7)) * 8;
  const int sw1 = ((4 + kg) ^ (ln & 7)) * 8;
  const int rae = (wr * (AH / 2) + ln) * 64;
  const int rbe = (wc * 32 + ln) * 64;

  f32x4 acc[2 * MF][4] = {};
  bf16x8 aA[MF][2], bB[2][2][2];  // a: one m-half; b: BOTH n-halves resident

#define LDA_(dd, mh)                                                              \
  { _Pragma("unroll") for (int mf = 0; mf < MF; ++mf) {                           \
      aA[mf][0] = *(const bf16x8*)&Asm[dd][mh][rae + mf * 1024 + sw0];            \
      aA[mf][1] = *(const bf16x8*)&Asm[dd][mh][rae + mf * 1024 + sw1];            \
    } }
#define LDB_(dd, bh)                                                              \
  { _Pragma("unroll") for (int nf = 0; nf < 2; ++nf) {                            \
      bB[bh][nf][0] = *(const bf16x8*)&Bsm[dd][bh][rbe + nf * 1024 + sw0];        \
      bB[bh][nf][1] = *(const bf16x8*)&Bsm[dd][bh][rbe + nf * 1024 + sw1];        \
    } }

#define QMM(mh, bh)                                                               \
  {                                                                               \
    __builtin_amdgcn_s_setprio(1);                                                \
    _Pragma("unroll") for (int mf = 0; mf < MF; ++mf)                             \
        _Pragma("unroll") for (int nf = 0; nf < 2; ++nf) {                        \
      acc[(mh)*MF + mf][(bh)*2 + nf] = __builtin_amdgcn_mfma_f32_16x16x32_bf16(   \
          aA[mf][0], bB[bh][nf][0], acc[(mh)*MF + mf][(bh)*2 + nf], 0, 0, 0);     \
      acc[(mh)*MF + mf][(bh)*2 + nf] = __builtin_amdgcn_mfma_f32_16x16x32_bf16(   \
          aA[mf][1], bB[bh][nf][1], acc[(mh)*MF + mf][(bh)*2 + nf], 0, 0, 0);     \
    }                                                                             \
    __builtin_amdgcn_s_setprio(0);                                                \
  }

#define BAR   { __builtin_amdgcn_s_barrier(); __builtin_amdgcn_sched_barrier(0); }
#define VWAIT                                                                     \
  { if (BM == 256) { asm volatile("s_waitcnt vmcnt(4)" ::: "memory"); }           \
    else { asm volatile("s_waitcnt vmcnt(3)" ::: "memory"); } }
#define VW0   { asm volatile("s_waitcnt vmcnt(0)" ::: "memory"); }

  // prologue: tile0 complete (dbuf0); tile1 partial (dbuf1: Ah0, Bh1)
  STA_(0, 0, 0); STB_(0, 0, 0); STB_(0, 1, 0); STA_(0, 1, 0);
  STA_(1, 0, 1); STB_(1, 1, 1);
  VWAIT;

  for (int T = 0; T < NT; T += 2) {
    const bool more = (T + 2) < NT;
    // p1: tile T (dbuf0), quadrant (mh0,bh0)
    LDA_(0, 0); LDB_(0, 0);
    STB_(1, 0, T + 1);
    BAR; QMM(0, 0); BAR;
    // p2: (mh0,bh1)
    LDB_(0, 1);
    STA_(1, 1, T + 1);
    BAR; QMM(0, 1); BAR;
    // p3: (mh1,bh1)
    LDA_(0, 1);
    if (more) STA_(0, 0, T + 2);
    BAR; QMM(1, 1); BAR;
    // p4: (mh1,bh0) — no ds loads
    if (more) { STB_(0, 1, T + 2); VWAIT; } else { VW0; }
    BAR; QMM(1, 0); BAR;
    // p5: tile T+1 (dbuf1), (mh0,bh0)
    LDA_(1, 0); LDB_(1, 0);
    if (more) STB_(0, 0, T + 2);
    BAR; QMM(0, 0); BAR;
    // p6: (mh0,bh1)
    LDB_(1, 1);
    if (more) STA_(0, 1, T + 2);
    BAR; QMM(0, 1); BAR;
    // p7: (mh1,bh1)
    LDA_(1, 1);
    if (more) STA_(1, 0, T + 3);
    BAR; QMM(1, 1); BAR;
    // p8: (mh1,bh0)
    if (more) { STB_(1, 1, T + 3); VWAIT; }
    BAR; QMM(1, 0); BAR;
  }

  // epilogue
  const int mat = bn >> 3;
  unsigned short* Cb = (unsigned short*)C;
  float* Cf = (float*)C;
#pragma unroll
  for (int mh = 0; mh < 2; ++mh)
#pragma unroll
    for (int mf = 0; mf < MF; ++mf)
#pragma unroll
      for (int j = 0; j < 4; ++j) {
        int row = m0 + mh * AH + wr * (AH / 2) + mf * 16 + kg * 4 + j;
        size_t rb = (size_t)mat * 8388608 + (size_t)row * 2048 + (size_t)((bn & 7) * 256);
#pragma unroll
        for (int bh = 0; bh < 2; ++bh)
#pragma unroll
          for (int nf = 0; nf < 2; ++nf) {
            int col = bh * 128 + wc * 32 + nf * 16 + ln;
            float v = acc[mh * MF + mf][bh * 2 + nf][j];
            if (OUT_F32) Cf[rb + col] = v;
            else Cb[rb + col] = f2b(v);
          }
      }
#undef STA_
#undef STB_
#undef LDA_
#undef LDB_
#undef QMM
#undef BAR
#undef VWAIT
#undef VW0
}

// ---------- flash attention v3 (unchanged) ----------
__global__ __launch_bounds__(256, 2) void attn3_kernel(const unsigned short* __restrict__ Qb,
                                                       const unsigned short* __restrict__ Kb,
                                                       const unsigned short* __restrict__ Vt,
                                                       unsigned short* __restrict__ Ob) {
  __shared__ unsigned short KS[2][8192];
  __shared__ unsigned short VS[2][8192];
  __shared__ unsigned short PS[4][2048];
  const int D = 2048, L = 2048;
  int tid = threadIdx.x, lane = tid & 63, w = tid >> 6;
  int ln = lane & 15, kg = lane >> 4;
  int bid = blockIdx.x;
  int g = bid >> 5, bh = bid & 31;
  int qt = (g < 8) ? (15 - g) : (g - 8);
  int b = bh >> 4, h = bh & 15;
  const size_t base = (size_t)b * L * D + h * 128;
  const unsigned short* Kp = Kb + base;
  const unsigned short* Qp = Qb + base;
  unsigned short* Op = Ob + base;
  const unsigned short* Vp = Vt + (size_t)bh * 128 * L;

  int q0 = qt * 128;
  int qw0 = q0 + w * 32;

  bf16x8 aq[2][4];
#pragma unroll
  for (int m = 0; m < 2; ++m)
#pragma unroll
    for (int kc = 0; kc < 4; ++kc)
      aq[m][kc] = *(const bf16x8*)&Qp[(size_t)(qw0 + m * 16 + ln) * D + kc * 32 + kg * 8];

  f32x4 o[2][8] = {};
  float m2[2][4], ls[2][4];
#pragma unroll
  for (int m = 0; m < 2; ++m)
#pragma unroll
    for (int j = 0; j < 4; ++j) { m2[m][j] = -1e30f; ls[m][j] = 0.f; }

  int l16 = lane >> 4, l8 = lane >> 3, l7 = lane & 7;

#define STAGE(T, NB)                                                                   \
  {                                                                                    \
    int kv0_ = (T) << 6;                                                               \
    _Pragma("unroll") for (int i = 0; i < 4; ++i) {                                    \
      int cK = w * 4 + i;                                                              \
      int r = cK * 4 + l16;                                                            \
      int sw = ln ^ (r & 7);                                                           \
      gl_lds16(Kp + (size_t)(kv0_ + r) * D + sw * 8, &KS[NB][cK * 512 + lane * 8]);    \
      int dh = cK * 8 + l8;                                                            \
      int sv = l7 ^ (dh & 7);                                                          \
      gl_lds16(Vp + (size_t)dh * L + kv0_ + sv * 8, &VS[NB][cK * 512 + lane * 8]);     \
    }                                                                                  \
  }

  int nt = 2 * qt + 2;
  int mask_t = 2 * qt + (w >> 1);

  STAGE(0, 0);
  __syncthreads();

  for (int t = 0; t < nt; ++t) {
    int cur = t & 1;
    if (t + 1 < nt) STAGE(t + 1, cur ^ 1);

    if (t <= mask_t) {
      int kv0 = t << 6;
      f32x4 s[2][4] = {};
#pragma unroll
      for (int n = 0; n < 4; ++n)
#pragma unroll
        for (int kc = 0; kc < 4; ++kc) {
          bf16x8 bk = *(const bf16x8*)&KS[cur][(n * 16 + ln) * 128 + (((kc << 2) + kg) ^ (ln & 7)) * 8];
          s[0][n] = __builtin_amdgcn_mfma_f32_16x16x32_bf16(aq[0][kc], bk, s[0][n], 0, 0, 0);
          s[1][n] = __builtin_amdgcn_mfma_f32_16x16x32_bf16(aq[1][kc], bk, s[1][n], 0, 0, 0);
        }
      if (t == mask_t) {
#pragma unroll
        for (int m = 0; m < 2; ++m)
#pragma unroll
          for (int n = 0; n < 4; ++n)
#pragma unroll
            for (int j = 0; j < 4; ++j)
              if (kv0 + n * 16 + ln > qw0 + m * 16 + kg * 4 + j) s[m][n][j] = -1e30f;
      }
      float pmax[2][4];
      bool near = true;
#pragma unroll
      for (int m = 0; m < 2; ++m)
#pragma unroll
        for (int j = 0; j < 4; ++j) {
          pmax[m][j] = fmaxf(fmaxf(s[m][0][j], s[m][1][j]), fmaxf(s[m][2][j], s[m][3][j]));
          near = near && (pmax[m][j] <= m2[m][j] + 8.0f);
        }
      if (!__all(near)) {
#pragma unroll
        for (int m = 0; m < 2; ++m)
#pragma unroll
          for (int j = 0; j < 4; ++j) {
            float mx = pmax[m][j];
#pragma unroll
            for (int d = 1; d < 16; d <<= 1) mx = fmaxf(mx, __shfl_xor(mx, d));
            mx = fmaxf(mx, m2[m][j]);
            float al = __builtin_amdgcn_exp2f(m2[m][j] - mx);
            m2[m][j] = mx;
            ls[m][j] *= al;
#pragma unroll
            for (int dt = 0; dt < 8; ++dt) o[m][dt][j] *= al;
          }
      }
#pragma unroll
      for (int m = 0; m < 2; ++m)
#pragma unroll
        for (int j = 0; j < 4; ++j) {
          int row = m * 16 + kg * 4 + j;
          float acc = 0.f;
#pragma unroll
          for (int n = 0; n < 4; ++n) {
            float p = __builtin_amdgcn_exp2f(s[m][n][j] - m2[m][j]);
            acc += p;
            unsigned int u = __builtin_bit_cast(unsigned int, p);
            PS[w][row * 64 + (((n * 2 + (ln >> 3)) ^ (row & 7)) * 8) + (ln & 7)] =
                (unsigned short)(u >> 16);
          }
          ls[m][j] += acc;
        }
#pragma unroll
      for (int kst = 0; kst < 2; ++kst) {
        bf16x8 ap0 = *(const bf16x8*)&PS[w][(ln) * 64 + (((kst << 2) + kg) ^ (ln & 7)) * 8];
        bf16x8 ap1 = *(const bf16x8*)&PS[w][(16 + ln) * 64 + (((kst << 2) + kg) ^ (ln & 7)) * 8];
#pragma unroll
        for (int dt = 0; dt < 8; ++dt) {
          bf16x8 bv = *(const bf16x8*)&VS[cur][(dt * 16 + ln) * 64 + (((kst << 2) + kg) ^ (ln & 7)) * 8];
          o[0][dt] = __builtin_amdgcn_mfma_f32_16x16x32_bf16(ap0, bv, o[0][dt], 0, 0, 0);
          o[1][dt] = __builtin_amdgcn_mfma_f32_16x16x32_bf16(ap1, bv, o[1][dt], 0, 0, 0);
        }
      }
    }
    __syncthreads();
  }
#undef STAGE

#pragma unroll
  for (int m = 0; m < 2; ++m)
#pragma unroll
    for (int j = 0; j < 4; ++j) {
      float tsum = ls[m][j];
#pragma unroll
      for (int d = 1; d < 16; d <<= 1) tsum += __shfl_xor(tsum, d);
      float inv = 1.0f / tsum;
      int row = qw0 + m * 16 + kg * 4 + j;
#pragma unroll
      for (int dt = 0; dt < 8; ++dt)
        Op[(size_t)row * D + dt * 16 + ln] = f2b(o[m][dt][j] * inv);
    }
}

// ---------- launch ----------
extern "C" void kernel_launch(void* const* d_in, const int* in_sizes, int n_in,
                              void* d_out, int out_size, void* d_ws, size_t ws_size,
                              hipStream_t stream) {
  const float* x  = (const float*)d_in[0];
  // d_in[1] = mask (causal; applied analytically)
  const float* Wq = (const float*)d_in[2];
  const float* Wk = (const float*)d_in[3];
  const float* Wv = (const float*)d_in[4];
  const float* Wo = (const float*)d_in[5];

  char* ws = (char*)d_ws;
  unsigned short* xb  = (unsigned short*)(ws + 0);
  unsigned short* wqb = (unsigned short*)(ws + 16777216);  // wq|wk|wv contiguous = [6144][2048]
  unsigned short* wkb = (unsigned short*)(ws + 25165824);
  unsigned short* wvb = (unsigned short*)(ws + 33554432);
  unsigned short* wob = (unsigned short*)(ws + 41943040);
  unsigned short* qb  = (unsigned short*)(ws + 50331648);  // q|k|v contiguous outputs
  unsigned short* kb  = (unsigned short*)(ws + 67108864);
  unsigned short* vb  = (unsigned short*)(ws + 83886080);
  float2* tab         = (float2*)(ws + 100663296);
  unsigned short* vt  = wqb;  // reuse wq+wk region after QKV GEMM
  unsigned short* ob  = xb;

  float* out  = (float*)d_out;
  float* kout = out + 8388608;
  float* vout = out + 16777216;

  cast_kernel<<<8192, 256, 0, stream>>>(x, xb, 2097152);
  cast4_kernel<<<dim3(4096, 4), 256, 0, stream>>>(Wq, Wk, Wv, Wo, wqb, wkb, wvb, wob, 1048576);
  rope_table_kernel<<<512, 256, 0, stream>>>(tab);

  // fused QKV GEMM: [4096x2048] x [6144x2048]^T -> q|k|v  (384 blocks, BM=256)
  gemm4<256, 24, 0><<<384, 512, 0, stream>>>(xb, wqb, qb);

  transpose_v_kernel<<<dim3(64, 4, 32), 256, 0, stream>>>(vb, vt);

  rope_apply_kernel<<<dim3(16384, 3), 256, 0, stream>>>(qb, kb, vb, kout, vout, tab);

  attn3_kernel<<<512, 256, 0, stream>>>(qb, kb, vt, ob);

  // output projection (256 blocks, BM=128)
  gemm4<128, 8, 1><<<256, 512, 0, stream>>>(ob, wob, out);
}